// Round 8
// baseline (8417.839 us; speedup 1.0000x reference)
//
#include <hip/hip_runtime.h>

#define F     4096
#define T     2048
#define NBLK  256
#define NTHR  1024
#define K     4      // ring slots; lockstep bounds skew so K>=2 is safe

// d_ws layout (NOTHING memset; harness re-poisons d_ws to 0xAA each launch):
//   [4096, 4096 + K*F*4) : ring[K][4096] u32 pairs {tag u16 << 16 | f16 bits}.
//   Poison 0xAAAAAAAA -> tag 0xAAAA = 43690, never equals a real tag (1..2049).
//   Data IS the flag: a pair is valid iff its tag matches; producer stores are
//   fire-and-forget; consumers accept fresh chunks immediately (overlapped).
//
// SESSION RECORD:
//   baseline 2-barrier/16-poller: 6950-6969 us (verified 3x, spread <0.3%)
//   R1 scattered 4B publishes:        9091 us (+30%)  [reverted]
//   R2 barrier-free all-wave spin:    8053 us (+16%)  [reverted]
//   R3 wave0-only spin, no sync(A):   7899 us (+13.5%)[reverted]
//   R4 lane-par combine + setprio:    7710 us (+11%)  [reverted]
//   R6 staging in waves 0-7 only:     6603 us (-5%)   poll-contention WIN
//   R7 waves 0-3 only + 16B-stride:   6459 us (-2.2%) WIN, conflicts back to 0
// Lessons: coalesced 16-lane publish is sacred; s_barrier sleep is cheap,
// spinning waves are expensive; step cadence scales with concurrent poll
// streams during the publish-visibility window (dose-response 16/8/4 pollers).
//
// R8 (this file): pollers 4 -> 2 (waves 2,3; 2048 elems each via 16 indep u64
// loads/lane), AND role separation: wave0 = pure publisher, wave1 = pure
// readout-store, waves 2,3 = pure pollers. Removes the publish->poll-issue
// serialization that existed when wave0 was both publisher and poller.
// Publish path, barriers, matvec, reductions: byte-identical to baseline.

typedef unsigned long long u64;
typedef unsigned int u32;
typedef unsigned short u16;

template <int CTRL>
__device__ __forceinline__ float dpp_add(float x) {
    int xi = __builtin_bit_cast(int, x);
    int yi = __builtin_amdgcn_update_dpp(0, xi, CTRL, 0xf, 0xf, false);
    return x + __builtin_bit_cast(float, yi);
}

// Full wave64 sum; total lands in lane 63. VALU-only.
__device__ __forceinline__ float wave_sum(float x) {
    x = dpp_add<0x111>(x); // row_shr:1
    x = dpp_add<0x112>(x); // row_shr:2
    x = dpp_add<0x114>(x); // row_shr:4
    x = dpp_add<0x118>(x); // row_shr:8
    x = dpp_add<0x142>(x); // row_bcast:15
    x = dpp_add<0x143>(x); // row_bcast:31
    return x;
}

#define PIN4(v) asm volatile("" : "+v"((v).x), "+v"((v).y), "+v"((v).z), "+v"((v).w))

__device__ __forceinline__ u64 cload_u64(const u64* p) {
    return __hip_atomic_load(p, __ATOMIC_RELAXED, __HIP_MEMORY_SCOPE_AGENT);
}
__device__ __forceinline__ void cstore_u32(u32* p, u32 v) {
    __hip_atomic_store(p, v, __ATOMIC_RELAXED, __HIP_MEMORY_SCOPE_AGENT);
}

__device__ __forceinline__ float half_to_f(u32 bits) {
    return (float)__builtin_bit_cast(_Float16, (u16)(bits & 0xffffu));
}

__device__ __forceinline__ bool pair_ok(u64 p, u32 tag) {
    return ((u32)(p & 0xffffffffu) >> 16 == tag)
         & ((u32)(p >> 32) >> 16 == tag);
}

__device__ __forceinline__ float4 pairs_to_f4(u64 a, u64 b) {
    float4 v;
    v.x = half_to_f((u32)(a & 0xffffffffu));
    v.y = half_to_f((u32)(a >> 32));
    v.z = half_to_f((u32)(b & 0xffffffffu));
    v.w = half_to_f((u32)(b >> 32));
    return v;
}

__global__ __launch_bounds__(NTHR, 4) void rc_kernel(
    const float* __restrict__ x, const float* __restrict__ Wres,
    const float* __restrict__ wout, float* __restrict__ out,
    u32* __restrict__ ring)
{
    __shared__ __align__(16) float fl[F];     // staged feats vector (16 KB)
    __shared__ float red[2][16][4];           // double-buffered matvec partials
    __shared__ float redo[2][16];             // double-buffered readout partials

    const int tid  = threadIdx.x;
    const int b    = blockIdx.x;
    const int w    = tid >> 6;
    const int lane = tid & 63;
    const int wr   = w & 3;   // row-group (4 rows each)
    const int wk   = w >> 2;  // k-group (1024 k each)

    // ---- persistent W_res fragment: 4 rows x 16 k = 64 fp32 regs/lane ----
    const int row0 = b * 16 + wr * 4;
    const int kofs = wk * 1024 + lane * 4;
    float4 wreg[4][4];
#pragma unroll
    for (int j = 0; j < 4; ++j) {
        const float* wp = Wres + (size_t)(row0 + j) * F + kofs;
#pragma unroll
        for (int i = 0; i < 4; ++i)
            wreg[j][i] = *(const float4*)(wp + i * 256);
    }
#pragma unroll
    for (int j = 0; j < 4; ++j) {
        PIN4(wreg[j][0]); PIN4(wreg[j][1]); PIN4(wreg[j][2]); PIN4(wreg[j][3]);
    }

    // ---- persistent w_out fragment (fused readout): 8 fp32 regs/lane ----
    const int rrow = b * 2 + (wr & 1);
    const int i0   = (wr >> 1) * 2;
    const float* wop = wout + (size_t)rrow * F + kofs + i0 * 256;
    float4 wo0 = *(const float4*)(wop);
    float4 wo1 = *(const float4*)(wop + 256);
    PIN4(wo0); PIN4(wo1);

    // ---- x prefetch for step 0 (publisher wave 0) ----
    float xval = 0.f;
    if (tid < 16) xval = x[(size_t)(b * 16 + tid) * T + 0];

    // staging base for poller waves 2,3: wave owns 2048 elems, 8 groups of
    // 256 elems, lane slice = 4 elems per group (16B-stride writes: no cfl)
    const int sb = (w - 2) * 2048 + lane * 4;

    for (int t = 0; t <= T; ++t) {
        // ---- 1. waves 2,3 poll feats_{t-1} pairs and stage to LDS;
        //         all other waves go straight to sync(L) and sleep (cheap) ----
        if (t > 0) {
            if (w == 2 || w == 3) {
                const u32* rs = ring + (size_t)((t - 1) & (K - 1)) * F + sb;
                const u32 tag = (u32)t;
                // 16 independent u64 loads = 32 packed pairs {tag16|f16}
                u64 pa[8], pb[8];
                bool ok[8];
#define LOADG(j) \
                pa[j] = cload_u64((const u64*)(rs + (j) * 256)); \
                pb[j] = cload_u64((const u64*)(rs + (j) * 256 + 2)); \
                ok[j] = pair_ok(pa[j], tag) & pair_ok(pb[j], tag);
                LOADG(0) LOADG(1) LOADG(2) LOADG(3)
                LOADG(4) LOADG(5) LOADG(6) LOADG(7)
                bool all8 = ok[0] & ok[1] & ok[2] & ok[3]
                          & ok[4] & ok[5] & ok[6] & ok[7];
                while (!__all(all8)) {
                    __builtin_amdgcn_s_sleep(1);
#define RETRYG(j) if (!ok[j]) { LOADG(j) }
                    RETRYG(0) RETRYG(1) RETRYG(2) RETRYG(3)
                    RETRYG(4) RETRYG(5) RETRYG(6) RETRYG(7)
#undef RETRYG
#undef LOADG
                    all8 = ok[0] & ok[1] & ok[2] & ok[3]
                         & ok[4] & ok[5] & ok[6] & ok[7];
                }
#pragma unroll
                for (int j = 0; j < 8; ++j)
                    *(float4*)&fl[sb + j * 256] = pairs_to_f4(pa[j], pb[j]);
            }
        } else {
            if (w == 2 || w == 3) {  // feats_{-1} = 0
                const float4 z = make_float4(0.f, 0.f, 0.f, 0.f);
#pragma unroll
                for (int j = 0; j < 8; ++j)
                    *(float4*)&fl[sb + j * 256] = z;
            }
        }
        __syncthreads();  // (L) feats staged

        // ---- 2. matvec from LDS + fused readout partial ----
        float4 f0 = *(const float4*)&fl[kofs + 0 * 256];
        float4 f1 = *(const float4*)&fl[kofs + 1 * 256];
        float4 f2 = *(const float4*)&fl[kofs + 2 * 256];
        float4 f3 = *(const float4*)&fl[kofs + 3 * 256];

        float acc0 = 0.f, acc1 = 0.f, acc2 = 0.f, acc3 = 0.f;
#define DOT_STEP(i, fv) \
        acc0 += wreg[0][i].x * fv.x + wreg[0][i].y * fv.y + wreg[0][i].z * fv.z + wreg[0][i].w * fv.w; \
        acc1 += wreg[1][i].x * fv.x + wreg[1][i].y * fv.y + wreg[1][i].z * fv.z + wreg[1][i].w * fv.w; \
        acc2 += wreg[2][i].x * fv.x + wreg[2][i].y * fv.y + wreg[2][i].z * fv.z + wreg[2][i].w * fv.w; \
        acc3 += wreg[3][i].x * fv.x + wreg[3][i].y * fv.y + wreg[3][i].z * fv.z + wreg[3][i].w * fv.w;
        DOT_STEP(0, f0)
        DOT_STEP(1, f1)
        DOT_STEP(2, f2)
        DOT_STEP(3, f3)
#undef DOT_STEP

        float4 ra, rb;
        if (i0 == 0) { ra = f0; rb = f1; } else { ra = f2; rb = f3; }
        float p = wo0.x * ra.x + wo0.y * ra.y + wo0.z * ra.z + wo0.w * ra.w
                + wo1.x * rb.x + wo1.y * rb.y + wo1.z * rb.z + wo1.w * rb.w;

        // ---- 3. wave reduce, lane63 -> LDS (double-buffered by t&1) ----
        acc0 = wave_sum(acc0);
        acc1 = wave_sum(acc1);
        acc2 = wave_sum(acc2);
        acc3 = wave_sum(acc3);
        p    = wave_sum(p);
        const int pb = t & 1;
        if (lane == 63) {
            red[pb][w][0] = acc0; red[pb][w][1] = acc1;
            red[pb][w][2] = acc2; red[pb][w][3] = acc3;
            redo[pb][w] = p;
        }
        __syncthreads();  // (A)

        // ---- 4. wave 0 (pure publisher): combine, clamp, coalesced publish ----
        if (w == 0 && t < T) {
            if (lane < 16) {
                const int r = lane, rw = r >> 2, rj = r & 3;
                float s = red[pb][rw][rj] + red[pb][rw + 4][rj]
                        + red[pb][rw + 8][rj] + red[pb][rw + 12][rj];
                s += xval;
                s = fminf(1.f, fmaxf(-1.f, s));
                u32 hb = (u32)__builtin_bit_cast(u16, (_Float16)s);
                u32 pk = ((u32)(t + 1) << 16) | hb;
                cstore_u32(ring + (size_t)(t & (K - 1)) * F + b * 16 + r, pk);
                const int tn = (t + 1 < T) ? (t + 1) : (T - 1);
                xval = x[(size_t)(b * 16 + lane) * T + tn];  // off critical path
            }
        }

        // ---- 5. out[:, t-1] store (wave 1; off the publish & poll paths) ----
        if (t > 0 && tid >= 64 && tid < 66) {
            const int r = tid - 64;
            float s = redo[pb][r]      + redo[pb][r + 2]  + redo[pb][r + 4]
                    + redo[pb][r + 6]  + redo[pb][r + 8]  + redo[pb][r + 10]
                    + redo[pb][r + 12] + redo[pb][r + 14];
            out[(size_t)(b * 2 + r) * T + (t - 1)] = s;
        }
        // red/redo double-buffered; fl rewrite at t+1 (pollers, after their
        // sync(A) at t) separated from all consumers' fl reads at t by sync(A);
        // ring slot reuse: block publishes step t only after ALL blocks
        // published t-1 (lockstep), so oldest in-flight reads are step t-1
        // -> K>=2 safe, K=4 used. No capacity counters needed.
    }
}

extern "C" void kernel_launch(void* const* d_in, const int* in_sizes, int n_in,
                              void* d_out, int out_size, void* d_ws, size_t ws_size,
                              hipStream_t stream) {
    const float* x    = (const float*)d_in[0];
    const float* Wres = (const float*)d_in[1];
    const float* wout = (const float*)d_in[2];
    float* out        = (float*)d_out;
    u32* ring         = (u32*)((char*)d_ws + 4096);

    // no memset: ring tags are self-describing; 0xAA poison never matches.

    void* args[] = { (void*)&x, (void*)&Wres, (void*)&wout, (void*)&out,
                     (void*)&ring };
    (void)hipLaunchCooperativeKernel((const void*)rc_kernel, dim3(NBLK), dim3(NTHR),
                                     args, 0, stream);
}

// Round 9
// 6615.650 us; speedup vs baseline: 1.2724x; 1.2724x over previous
//
#include <hip/hip_runtime.h>

#define F     4096
#define T     2048
#define NBLK  256
#define NTHR  1024
#define K     4      // ring slots; lockstep bounds skew so K>=2 is safe

// d_ws layout (NOTHING memset; harness re-poisons d_ws to 0xAA each launch):
//   [4096, 4096 + K*F*4) : ring[K][4096] u32 pairs {tag u16 << 16 | f16 bits}.
//   Poison 0xAAAAAAAA -> tag 0xAAAA = 43690, never equals a real tag (1..2049).
//   Data IS the flag: a pair is valid iff its tag matches; producer stores are
//   fire-and-forget; consumers accept fresh chunks immediately (overlapped).
//
// SESSION RECORD:
//   baseline 2-barrier/16-poller: 6950-6969 us (verified 3x, spread <0.3%)
//   R1 scattered 4B publishes:        9091 us (+30%)  [reverted]
//   R2 barrier-free all-wave spin:    8053 us (+16%)  [reverted]
//   R3 wave0-only spin, no sync(A):   7899 us (+13.5%)[reverted]
//   R4 lane-par combine + setprio:    7710 us (+11%)  [reverted]
//   R6 staging in waves 0-7 only:     6603 us (-5%)   poll-contention WIN
//   R7 waves 0-3 only + 16B-stride:   6459 us (-2.2%) WIN, conflicts 0
//   R8 2 pollers + role separation:   8418 us (+30%)  [reverted: REG SPILL --
//      WRITE 36.9->95MB scratch writeback, SGPR 112, VALUBusy 24.6%; and 16
//      in-flight u64/lane over-serializes detect]
// Poller dose-response: 16->6958, 8->6603, 4->6459, 2->spill. 4 is optimal.
//
// R9 (this file): R7 exactly, with the ONE clean idea from R8 isolated:
// staging moved from waves 0-3 to waves 4-7 (still 4 pollers, one per SIMD,
// same 8-u64-in-flight footprint -> no spill). Wave0 becomes a PURE publisher:
// its next-step poll no longer queues behind its publish store, so all four
// pollers issue immediately at sync(A) release, overlapped with the publish.
// Publish path, barriers, matvec, reductions: byte-identical to R7/baseline.

typedef unsigned long long u64;
typedef unsigned int u32;
typedef unsigned short u16;

template <int CTRL>
__device__ __forceinline__ float dpp_add(float x) {
    int xi = __builtin_bit_cast(int, x);
    int yi = __builtin_amdgcn_update_dpp(0, xi, CTRL, 0xf, 0xf, false);
    return x + __builtin_bit_cast(float, yi);
}

// Full wave64 sum; total lands in lane 63. VALU-only.
__device__ __forceinline__ float wave_sum(float x) {
    x = dpp_add<0x111>(x); // row_shr:1
    x = dpp_add<0x112>(x); // row_shr:2
    x = dpp_add<0x114>(x); // row_shr:4
    x = dpp_add<0x118>(x); // row_shr:8
    x = dpp_add<0x142>(x); // row_bcast:15
    x = dpp_add<0x143>(x); // row_bcast:31
    return x;
}

#define PIN4(v) asm volatile("" : "+v"((v).x), "+v"((v).y), "+v"((v).z), "+v"((v).w))

__device__ __forceinline__ u64 cload_u64(const u64* p) {
    return __hip_atomic_load(p, __ATOMIC_RELAXED, __HIP_MEMORY_SCOPE_AGENT);
}
__device__ __forceinline__ void cstore_u32(u32* p, u32 v) {
    __hip_atomic_store(p, v, __ATOMIC_RELAXED, __HIP_MEMORY_SCOPE_AGENT);
}

__device__ __forceinline__ float half_to_f(u32 bits) {
    return (float)__builtin_bit_cast(_Float16, (u16)(bits & 0xffffu));
}

__device__ __forceinline__ bool pair_ok(u64 p, u32 tag) {
    return ((u32)(p & 0xffffffffu) >> 16 == tag)
         & ((u32)(p >> 32) >> 16 == tag);
}

__device__ __forceinline__ float4 pairs_to_f4(u64 a, u64 b) {
    float4 v;
    v.x = half_to_f((u32)(a & 0xffffffffu));
    v.y = half_to_f((u32)(a >> 32));
    v.z = half_to_f((u32)(b & 0xffffffffu));
    v.w = half_to_f((u32)(b >> 32));
    return v;
}

__global__ __launch_bounds__(NTHR, 4) void rc_kernel(
    const float* __restrict__ x, const float* __restrict__ Wres,
    const float* __restrict__ wout, float* __restrict__ out,
    u32* __restrict__ ring)
{
    __shared__ __align__(16) float fl[F];     // staged feats vector (16 KB)
    __shared__ float red[2][16][4];           // double-buffered matvec partials
    __shared__ float redo[2][16];             // double-buffered readout partials

    const int tid  = threadIdx.x;
    const int b    = blockIdx.x;
    const int w    = tid >> 6;
    const int lane = tid & 63;
    const int wr   = w & 3;   // row-group (4 rows each)
    const int wk   = w >> 2;  // k-group (1024 k each)

    // ---- persistent W_res fragment: 4 rows x 16 k = 64 fp32 regs/lane ----
    const int row0 = b * 16 + wr * 4;
    const int kofs = wk * 1024 + lane * 4;
    float4 wreg[4][4];
#pragma unroll
    for (int j = 0; j < 4; ++j) {
        const float* wp = Wres + (size_t)(row0 + j) * F + kofs;
#pragma unroll
        for (int i = 0; i < 4; ++i)
            wreg[j][i] = *(const float4*)(wp + i * 256);
    }
#pragma unroll
    for (int j = 0; j < 4; ++j) {
        PIN4(wreg[j][0]); PIN4(wreg[j][1]); PIN4(wreg[j][2]); PIN4(wreg[j][3]);
    }

    // ---- persistent w_out fragment (fused readout): 8 fp32 regs/lane ----
    const int rrow = b * 2 + (wr & 1);
    const int i0   = (wr >> 1) * 2;
    const float* wop = wout + (size_t)rrow * F + kofs + i0 * 256;
    float4 wo0 = *(const float4*)(wop);
    float4 wo1 = *(const float4*)(wop + 256);
    PIN4(wo0); PIN4(wo1);

    // ---- x prefetch for step 0 (publisher wave 0) ----
    float xval = 0.f;
    if (tid < 16) xval = x[(size_t)(b * 16 + tid) * T + 0];

    // staging base for poller waves 4..7: wave owns elems [(w-4)*1024, +1024);
    // lane's group j = elems sb + j*256 .. +3 (16B-stride writes: no conflicts)
    const int sb = (w - 4) * 1024 + lane * 4;

    for (int t = 0; t <= T; ++t) {
        // ---- 1. waves 4-7 poll feats_{t-1} pairs and stage to LDS;
        //         all other waves go straight to sync(L) and sleep (cheap) ----
        if (t > 0) {
            if (w >= 4 && w < 8) {
                const u32* rs = ring + (size_t)((t - 1) & (K - 1)) * F + sb;
                const u32 tag = (u32)t;
                // 8 independent u64 loads = 16 packed pairs {tag16|f16}
                u64 pa0 = cload_u64((const u64*)(rs));
                u64 pa1 = cload_u64((const u64*)(rs + 2));
                u64 pb0 = cload_u64((const u64*)(rs + 256));
                u64 pb1 = cload_u64((const u64*)(rs + 258));
                u64 pc0 = cload_u64((const u64*)(rs + 512));
                u64 pc1 = cload_u64((const u64*)(rs + 514));
                u64 pd0 = cload_u64((const u64*)(rs + 768));
                u64 pd1 = cload_u64((const u64*)(rs + 770));
                bool oka = pair_ok(pa0, tag) & pair_ok(pa1, tag);
                bool okb = pair_ok(pb0, tag) & pair_ok(pb1, tag);
                bool okc = pair_ok(pc0, tag) & pair_ok(pc1, tag);
                bool okd = pair_ok(pd0, tag) & pair_ok(pd1, tag);
                while (!__all(oka & okb & okc & okd)) {
                    __builtin_amdgcn_s_sleep(1);
                    if (!oka) {
                        pa0 = cload_u64((const u64*)(rs));
                        pa1 = cload_u64((const u64*)(rs + 2));
                        oka = pair_ok(pa0, tag) & pair_ok(pa1, tag);
                    }
                    if (!okb) {
                        pb0 = cload_u64((const u64*)(rs + 256));
                        pb1 = cload_u64((const u64*)(rs + 258));
                        okb = pair_ok(pb0, tag) & pair_ok(pb1, tag);
                    }
                    if (!okc) {
                        pc0 = cload_u64((const u64*)(rs + 512));
                        pc1 = cload_u64((const u64*)(rs + 514));
                        okc = pair_ok(pc0, tag) & pair_ok(pc1, tag);
                    }
                    if (!okd) {
                        pd0 = cload_u64((const u64*)(rs + 768));
                        pd1 = cload_u64((const u64*)(rs + 770));
                        okd = pair_ok(pd0, tag) & pair_ok(pd1, tag);
                    }
                }
                *(float4*)&fl[sb]       = pairs_to_f4(pa0, pa1);
                *(float4*)&fl[sb + 256] = pairs_to_f4(pb0, pb1);
                *(float4*)&fl[sb + 512] = pairs_to_f4(pc0, pc1);
                *(float4*)&fl[sb + 768] = pairs_to_f4(pd0, pd1);
            }
        } else {
            if (w >= 4 && w < 8) {  // feats_{-1} = 0
                const float4 z = make_float4(0.f, 0.f, 0.f, 0.f);
                *(float4*)&fl[sb]       = z;
                *(float4*)&fl[sb + 256] = z;
                *(float4*)&fl[sb + 512] = z;
                *(float4*)&fl[sb + 768] = z;
            }
        }
        __syncthreads();  // (L) feats staged

        // ---- 2. matvec from LDS + fused readout partial ----
        float4 f0 = *(const float4*)&fl[kofs + 0 * 256];
        float4 f1 = *(const float4*)&fl[kofs + 1 * 256];
        float4 f2 = *(const float4*)&fl[kofs + 2 * 256];
        float4 f3 = *(const float4*)&fl[kofs + 3 * 256];

        float acc0 = 0.f, acc1 = 0.f, acc2 = 0.f, acc3 = 0.f;
#define DOT_STEP(i, fv) \
        acc0 += wreg[0][i].x * fv.x + wreg[0][i].y * fv.y + wreg[0][i].z * fv.z + wreg[0][i].w * fv.w; \
        acc1 += wreg[1][i].x * fv.x + wreg[1][i].y * fv.y + wreg[1][i].z * fv.z + wreg[1][i].w * fv.w; \
        acc2 += wreg[2][i].x * fv.x + wreg[2][i].y * fv.y + wreg[2][i].z * fv.z + wreg[2][i].w * fv.w; \
        acc3 += wreg[3][i].x * fv.x + wreg[3][i].y * fv.y + wreg[3][i].z * fv.z + wreg[3][i].w * fv.w;
        DOT_STEP(0, f0)
        DOT_STEP(1, f1)
        DOT_STEP(2, f2)
        DOT_STEP(3, f3)
#undef DOT_STEP

        float4 ra, rb;
        if (i0 == 0) { ra = f0; rb = f1; } else { ra = f2; rb = f3; }
        float p = wo0.x * ra.x + wo0.y * ra.y + wo0.z * ra.z + wo0.w * ra.w
                + wo1.x * rb.x + wo1.y * rb.y + wo1.z * rb.z + wo1.w * rb.w;

        // ---- 3. wave reduce, lane63 -> LDS (double-buffered by t&1) ----
        acc0 = wave_sum(acc0);
        acc1 = wave_sum(acc1);
        acc2 = wave_sum(acc2);
        acc3 = wave_sum(acc3);
        p    = wave_sum(p);
        const int pb = t & 1;
        if (lane == 63) {
            red[pb][w][0] = acc0; red[pb][w][1] = acc1;
            red[pb][w][2] = acc2; red[pb][w][3] = acc3;
            redo[pb][w] = p;
        }
        __syncthreads();  // (A)

        // ---- 4. wave 0 (pure publisher): combine, clamp, coalesced publish ----
        if (w == 0 && t < T) {
            if (lane < 16) {
                const int r = lane, rw = r >> 2, rj = r & 3;
                float s = red[pb][rw][rj] + red[pb][rw + 4][rj]
                        + red[pb][rw + 8][rj] + red[pb][rw + 12][rj];
                s += xval;
                s = fminf(1.f, fmaxf(-1.f, s));
                u32 hb = (u32)__builtin_bit_cast(u16, (_Float16)s);
                u32 pk = ((u32)(t + 1) << 16) | hb;
                cstore_u32(ring + (size_t)(t & (K - 1)) * F + b * 16 + r, pk);
                const int tn = (t + 1 < T) ? (t + 1) : (T - 1);
                xval = x[(size_t)(b * 16 + lane) * T + tn];  // off critical path
            }
        }

        // ---- 5. out[:, t-1] store (wave 1; off the publish & poll paths) ----
        if (t > 0 && tid >= 64 && tid < 66) {
            const int r = tid - 64;
            float s = redo[pb][r]      + redo[pb][r + 2]  + redo[pb][r + 4]
                    + redo[pb][r + 6]  + redo[pb][r + 8]  + redo[pb][r + 10]
                    + redo[pb][r + 12] + redo[pb][r + 14];
            out[(size_t)(b * 2 + r) * T + (t - 1)] = s;
        }
        // red/redo double-buffered; fl rewrite at t+1 (pollers, after their
        // sync(A) at t) separated from all consumers' fl reads at t by sync(A);
        // ring slot reuse: block publishes step t only after ALL blocks
        // published t-1 (lockstep), so oldest in-flight reads are step t-1
        // -> K>=2 safe, K=4 used. No capacity counters needed.
    }
}

extern "C" void kernel_launch(void* const* d_in, const int* in_sizes, int n_in,
                              void* d_out, int out_size, void* d_ws, size_t ws_size,
                              hipStream_t stream) {
    const float* x    = (const float*)d_in[0];
    const float* Wres = (const float*)d_in[1];
    const float* wout = (const float*)d_in[2];
    float* out        = (float*)d_out;
    u32* ring         = (u32*)((char*)d_ws + 4096);

    // no memset: ring tags are self-describing; 0xAA poison never matches.

    void* args[] = { (void*)&x, (void*)&Wres, (void*)&wout, (void*)&out,
                     (void*)&ring };
    (void)hipLaunchCooperativeKernel((const void*)rc_kernel, dim3(NBLK), dim3(NTHR),
                                     args, 0, stream);
}

// Round 10
// 6437.008 us; speedup vs baseline: 1.3077x; 1.0278x over previous
//
#include <hip/hip_runtime.h>

#define F     4096
#define T     2048
#define NBLK  256
#define NTHR  1024
#define K     4      // ring slots; lockstep bounds skew so K>=2 is safe

// d_ws layout (NOTHING memset; harness re-poisons d_ws to 0xAA each launch):
//   [4096, 4096 + K*F*4) : ring[K][4096] u32 pairs {tag u16 << 16 | f16 bits}.
//   Poison 0xAAAAAAAA -> tag 0xAAAA = 43690, never equals a real tag (1..2049).
//   Data IS the flag: a pair is valid iff its tag matches; producer stores are
//   fire-and-forget; consumers accept fresh chunks immediately (overlapped).
//
// SESSION RECORD (this file = R7, the verified session best):
//   baseline 2-barrier/16-poller: 6950-6969 us (verified 3x, spread <0.3%)
//   R1 scattered 4B publishes:        9091 us (+30%)  [reverted]
//   R2 barrier-free all-wave spin:    8053 us (+16%)  [reverted]
//   R3 wave0-only spin, no sync(A):   7899 us (+13.5%)[reverted]
//   R4 lane-par combine + setprio:    7710 us (+11%)  [reverted]
//   R6 staging in waves 0-7 only:     6603 us (-5%)   poll-contention WIN
//   R7 waves 0-3 only + 16B-stride:   6459 us (-2.2%) WIN  <- THIS KERNEL
//   R8 2 pollers (16 u64 in flight):  8418 us (+30%)  [reverted: reg spill]
//   R9 pollers moved to waves 4-7:    6616 us (+2.4%) [reverted: SIMD
//      arbitration publisher-vs-poller; R7's co-location is better]
// Poller dose-response: 16->6958, 8->6603, 4->6459, 2->spill. 4 is optimal.
// Lessons: coalesced 16-lane publish is sacred; s_barrier sleep is cheap,
// spinning waves are expensive; step cadence scales with concurrent poll
// streams during the publish-visibility window; the residual ~3.15us/step is
// the inter-block coherence RT (publish -> IC -> remote detect) x 2048
// sequential steps -- a latency floor, not a counter roofline.

typedef unsigned long long u64;
typedef unsigned int u32;
typedef unsigned short u16;

template <int CTRL>
__device__ __forceinline__ float dpp_add(float x) {
    int xi = __builtin_bit_cast(int, x);
    int yi = __builtin_amdgcn_update_dpp(0, xi, CTRL, 0xf, 0xf, false);
    return x + __builtin_bit_cast(float, yi);
}

// Full wave64 sum; total lands in lane 63. VALU-only.
__device__ __forceinline__ float wave_sum(float x) {
    x = dpp_add<0x111>(x); // row_shr:1
    x = dpp_add<0x112>(x); // row_shr:2
    x = dpp_add<0x114>(x); // row_shr:4
    x = dpp_add<0x118>(x); // row_shr:8
    x = dpp_add<0x142>(x); // row_bcast:15
    x = dpp_add<0x143>(x); // row_bcast:31
    return x;
}

#define PIN4(v) asm volatile("" : "+v"((v).x), "+v"((v).y), "+v"((v).z), "+v"((v).w))

__device__ __forceinline__ u64 cload_u64(const u64* p) {
    return __hip_atomic_load(p, __ATOMIC_RELAXED, __HIP_MEMORY_SCOPE_AGENT);
}
__device__ __forceinline__ void cstore_u32(u32* p, u32 v) {
    __hip_atomic_store(p, v, __ATOMIC_RELAXED, __HIP_MEMORY_SCOPE_AGENT);
}

__device__ __forceinline__ float half_to_f(u32 bits) {
    return (float)__builtin_bit_cast(_Float16, (u16)(bits & 0xffffu));
}

__device__ __forceinline__ bool pair_ok(u64 p, u32 tag) {
    return ((u32)(p & 0xffffffffu) >> 16 == tag)
         & ((u32)(p >> 32) >> 16 == tag);
}

__device__ __forceinline__ float4 pairs_to_f4(u64 a, u64 b) {
    float4 v;
    v.x = half_to_f((u32)(a & 0xffffffffu));
    v.y = half_to_f((u32)(a >> 32));
    v.z = half_to_f((u32)(b & 0xffffffffu));
    v.w = half_to_f((u32)(b >> 32));
    return v;
}

__global__ __launch_bounds__(NTHR, 4) void rc_kernel(
    const float* __restrict__ x, const float* __restrict__ Wres,
    const float* __restrict__ wout, float* __restrict__ out,
    u32* __restrict__ ring)
{
    __shared__ __align__(16) float fl[F];     // staged feats vector (16 KB)
    __shared__ float red[2][16][4];           // double-buffered matvec partials
    __shared__ float redo[2][16];             // double-buffered readout partials

    const int tid  = threadIdx.x;
    const int b    = blockIdx.x;
    const int w    = tid >> 6;
    const int lane = tid & 63;
    const int wr   = w & 3;   // row-group (4 rows each)
    const int wk   = w >> 2;  // k-group (1024 k each)

    // ---- persistent W_res fragment: 4 rows x 16 k = 64 fp32 regs/lane ----
    const int row0 = b * 16 + wr * 4;
    const int kofs = wk * 1024 + lane * 4;
    float4 wreg[4][4];
#pragma unroll
    for (int j = 0; j < 4; ++j) {
        const float* wp = Wres + (size_t)(row0 + j) * F + kofs;
#pragma unroll
        for (int i = 0; i < 4; ++i)
            wreg[j][i] = *(const float4*)(wp + i * 256);
    }
#pragma unroll
    for (int j = 0; j < 4; ++j) {
        PIN4(wreg[j][0]); PIN4(wreg[j][1]); PIN4(wreg[j][2]); PIN4(wreg[j][3]);
    }

    // ---- persistent w_out fragment (fused readout): 8 fp32 regs/lane ----
    const int rrow = b * 2 + (wr & 1);
    const int i0   = (wr >> 1) * 2;
    const float* wop = wout + (size_t)rrow * F + kofs + i0 * 256;
    float4 wo0 = *(const float4*)(wop);
    float4 wo1 = *(const float4*)(wop + 256);
    PIN4(wo0); PIN4(wo1);

    // ---- x prefetch for step 0 ----
    float xval = 0.f;
    if (tid < 16) xval = x[(size_t)(b * 16 + tid) * T + 0];

    // staging base for waves 0..3: wave w owns elems [w*1024, w*1024+1024);
    // lane's group j = elems sb + j*256 .. +3  (16B-stride writes: no conflicts)
    const int sb = w * 1024 + lane * 4;

    for (int t = 0; t <= T; ++t) {
        // ---- 1. waves 0-3 poll feats_{t-1} pairs and stage to LDS;
        //         waves 4-15 go straight to sync(L) and sleep (cheap) ----
        if (t > 0) {
            if (w < 4) {
                const u32* rs = ring + (size_t)((t - 1) & (K - 1)) * F + sb;
                const u32 tag = (u32)t;
                // 8 independent u64 loads = 16 packed pairs {tag16|f16}
                u64 pa0 = cload_u64((const u64*)(rs));
                u64 pa1 = cload_u64((const u64*)(rs + 2));
                u64 pb0 = cload_u64((const u64*)(rs + 256));
                u64 pb1 = cload_u64((const u64*)(rs + 258));
                u64 pc0 = cload_u64((const u64*)(rs + 512));
                u64 pc1 = cload_u64((const u64*)(rs + 514));
                u64 pd0 = cload_u64((const u64*)(rs + 768));
                u64 pd1 = cload_u64((const u64*)(rs + 770));
                bool oka = pair_ok(pa0, tag) & pair_ok(pa1, tag);
                bool okb = pair_ok(pb0, tag) & pair_ok(pb1, tag);
                bool okc = pair_ok(pc0, tag) & pair_ok(pc1, tag);
                bool okd = pair_ok(pd0, tag) & pair_ok(pd1, tag);
                while (!__all(oka & okb & okc & okd)) {
                    __builtin_amdgcn_s_sleep(1);
                    if (!oka) {
                        pa0 = cload_u64((const u64*)(rs));
                        pa1 = cload_u64((const u64*)(rs + 2));
                        oka = pair_ok(pa0, tag) & pair_ok(pa1, tag);
                    }
                    if (!okb) {
                        pb0 = cload_u64((const u64*)(rs + 256));
                        pb1 = cload_u64((const u64*)(rs + 258));
                        okb = pair_ok(pb0, tag) & pair_ok(pb1, tag);
                    }
                    if (!okc) {
                        pc0 = cload_u64((const u64*)(rs + 512));
                        pc1 = cload_u64((const u64*)(rs + 514));
                        okc = pair_ok(pc0, tag) & pair_ok(pc1, tag);
                    }
                    if (!okd) {
                        pd0 = cload_u64((const u64*)(rs + 768));
                        pd1 = cload_u64((const u64*)(rs + 770));
                        okd = pair_ok(pd0, tag) & pair_ok(pd1, tag);
                    }
                }
                *(float4*)&fl[sb]       = pairs_to_f4(pa0, pa1);
                *(float4*)&fl[sb + 256] = pairs_to_f4(pb0, pb1);
                *(float4*)&fl[sb + 512] = pairs_to_f4(pc0, pc1);
                *(float4*)&fl[sb + 768] = pairs_to_f4(pd0, pd1);
            }
        } else {
            if (w < 4) {  // feats_{-1} = 0
                const float4 z = make_float4(0.f, 0.f, 0.f, 0.f);
                *(float4*)&fl[sb]       = z;
                *(float4*)&fl[sb + 256] = z;
                *(float4*)&fl[sb + 512] = z;
                *(float4*)&fl[sb + 768] = z;
            }
        }
        __syncthreads();  // (L) feats staged

        // ---- 2. matvec from LDS + fused readout partial ----
        float4 f0 = *(const float4*)&fl[kofs + 0 * 256];
        float4 f1 = *(const float4*)&fl[kofs + 1 * 256];
        float4 f2 = *(const float4*)&fl[kofs + 2 * 256];
        float4 f3 = *(const float4*)&fl[kofs + 3 * 256];

        float acc0 = 0.f, acc1 = 0.f, acc2 = 0.f, acc3 = 0.f;
#define DOT_STEP(i, fv) \
        acc0 += wreg[0][i].x * fv.x + wreg[0][i].y * fv.y + wreg[0][i].z * fv.z + wreg[0][i].w * fv.w; \
        acc1 += wreg[1][i].x * fv.x + wreg[1][i].y * fv.y + wreg[1][i].z * fv.z + wreg[1][i].w * fv.w; \
        acc2 += wreg[2][i].x * fv.x + wreg[2][i].y * fv.y + wreg[2][i].z * fv.z + wreg[2][i].w * fv.w; \
        acc3 += wreg[3][i].x * fv.x + wreg[3][i].y * fv.y + wreg[3][i].z * fv.z + wreg[3][i].w * fv.w;
        DOT_STEP(0, f0)
        DOT_STEP(1, f1)
        DOT_STEP(2, f2)
        DOT_STEP(3, f3)
#undef DOT_STEP

        float4 ra, rb;
        if (i0 == 0) { ra = f0; rb = f1; } else { ra = f2; rb = f3; }
        float p = wo0.x * ra.x + wo0.y * ra.y + wo0.z * ra.z + wo0.w * ra.w
                + wo1.x * rb.x + wo1.y * rb.y + wo1.z * rb.z + wo1.w * rb.w;

        // ---- 3. wave reduce, lane63 -> LDS (double-buffered by t&1) ----
        acc0 = wave_sum(acc0);
        acc1 = wave_sum(acc1);
        acc2 = wave_sum(acc2);
        acc3 = wave_sum(acc3);
        p    = wave_sum(p);
        const int pb = t & 1;
        if (lane == 63) {
            red[pb][w][0] = acc0; red[pb][w][1] = acc1;
            red[pb][w][2] = acc2; red[pb][w][3] = acc3;
            redo[pb][w] = p;
        }
        __syncthreads();  // (A)

        // ---- 4. wave 0: combine, clamp, publish packed pair (store = flag) ----
        if (w == 0 && t < T) {
            if (lane < 16) {
                const int r = lane, rw = r >> 2, rj = r & 3;
                float s = red[pb][rw][rj] + red[pb][rw + 4][rj]
                        + red[pb][rw + 8][rj] + red[pb][rw + 12][rj];
                s += xval;
                s = fminf(1.f, fmaxf(-1.f, s));
                u32 hb = (u32)__builtin_bit_cast(u16, (_Float16)s);
                u32 pk = ((u32)(t + 1) << 16) | hb;
                cstore_u32(ring + (size_t)(t & (K - 1)) * F + b * 16 + r, pk);
                const int tn = (t + 1 < T) ? (t + 1) : (T - 1);
                xval = x[(size_t)(b * 16 + lane) * T + tn];  // off critical path
            }
        }

        // ---- 5. out[:, t-1] store (wave 1; off the publish path) ----
        if (t > 0 && tid >= 64 && tid < 66) {
            const int r = tid - 64;
            float s = redo[pb][r]      + redo[pb][r + 2]  + redo[pb][r + 4]
                    + redo[pb][r + 6]  + redo[pb][r + 8]  + redo[pb][r + 10]
                    + redo[pb][r + 12] + redo[pb][r + 14];
            out[(size_t)(b * 2 + r) * T + (t - 1)] = s;
        }
        // red/redo double-buffered; fl rewrite at t+1 separated by sync (A);
        // ring slot reuse: block publishes step t only after ALL blocks
        // published t-1 (lockstep), so oldest in-flight reads are step t-1
        // -> K>=2 safe, K=4 used. No capacity counters needed.
    }
}

extern "C" void kernel_launch(void* const* d_in, const int* in_sizes, int n_in,
                              void* d_out, int out_size, void* d_ws, size_t ws_size,
                              hipStream_t stream) {
    const float* x    = (const float*)d_in[0];
    const float* Wres = (const float*)d_in[1];
    const float* wout = (const float*)d_in[2];
    float* out        = (float*)d_out;
    u32* ring         = (u32*)((char*)d_ws + 4096);

    // no memset: ring tags are self-describing; 0xAA poison never matches.

    void* args[] = { (void*)&x, (void*)&Wres, (void*)&wout, (void*)&out,
                     (void*)&ring };
    (void)hipLaunchCooperativeKernel((const void*)rc_kernel, dim3(NBLK), dim3(NTHR),
                                     args, 0, stream);
}